// Round 3
// baseline (541.934 us; speedup 1.0000x reference)
//
#include <hip/hip_runtime.h>
#include <hip/hip_bf16.h>

// EdgeAttentionEmbedding collapsed form:
//   softmax([s,s]) == [0.5,0.5]  =>  attention branch (W2,b2,Wa,ba) is dead.
//   out[e] = row_softmax( a_e*(nf[u]+nf[v]) @ A + ef[e] @ Bm + c )
//   A  = 0.5*sum_h W1_h @ W3_h[:128]   (128x128)
//   Bm = 0.5*sum_h W3_h[128:192]       (64x128)
//   c  = sum_h b1_h @ W3_h[:128] + 0.5*sum_h b3_h
//   a_e = (u==v) ? 1.0 : 0.5
// y = nf @ A precomputed (bf16, 12.8 MB table). Edge kernel: gathers issued as
// early 16B-vectorized loads (latency hidden under staging+MFMA), redistributed
// to the MFMA output layout through a per-wave LDS scratch that unions over the
// dead ef/Bmt staging buffers. Streaming ef loads / out stores non-temporal.

#define NNODES 50000
#define NEDGES 640000

typedef __bf16 bf16;
typedef __bf16 bf16x4 __attribute__((ext_vector_type(4)));
typedef __bf16 bf16x8 __attribute__((ext_vector_type(8)));
typedef float f32x4 __attribute__((ext_vector_type(4)));

// ---------------------------------------------------------------- kernel 0
// Fold weights: At[c][k] = A[k][c] (bf16), Bmt[c][k] = Bm[k][c] (bf16), cvec f32.
__global__ void prep_kernel(const float* __restrict__ W1, const float* __restrict__ b1,
                            const float* __restrict__ W3, const float* __restrict__ b3,
                            bf16* __restrict__ At, bf16* __restrict__ Bmt,
                            float* __restrict__ cvec) {
    int j = threadIdx.x;   // output column 0..127
    int i = blockIdx.x;    // 0..127: A row i; 128: c + Bmt
    if (i < 128) {
        float acc = 0.f;
        for (int h = 0; h < 2; ++h) {
            const float* w1 = W1 + h * 128 * 128 + i * 128;
            const float* w3 = W3 + h * 192 * 128;
            for (int k = 0; k < 128; ++k)
                acc += w1[k] * w3[k * 128 + j];
        }
        At[j * 128 + i] = (bf16)(0.5f * acc);
    } else {
        float acc = 0.f;
        for (int h = 0; h < 2; ++h) {
            const float* w3 = W3 + h * 192 * 128;
            for (int k = 0; k < 128; ++k)
                acc += b1[h * 128 + k] * w3[k * 128 + j];
        }
        acc += 0.5f * (b3[j] + b3[128 + j]);
        cvec[j] = acc;
        for (int k = 0; k < 64; ++k) {
            float bm = 0.5f * (W3[(128 + k) * 128 + j] +
                               W3[192 * 128 + (128 + k) * 128 + j]);
            Bmt[j * 64 + k] = (bf16)bm;
        }
    }
}

// ---------------------------------------------------------------- kernel 1
// y[n][c] = (nf @ A)[n][c], bf16 out. Tile: 64 rows x 128 cols per block (4 waves).
#define K1_PAD 136   // 128 + 8 shorts: 272B rows (16B aligned), 2-way-bank-free

__global__ __launch_bounds__(256) void node_proj_kernel(
        const float* __restrict__ nf, const bf16* __restrict__ At_g,
        bf16* __restrict__ y) {
    __shared__ bf16 a_lds[64 * K1_PAD];
    __shared__ bf16 b_lds[128 * K1_PAD];
    const int t = threadIdx.x;
    const int m0 = blockIdx.x * 64;
    // stage nf tile (fp32 -> bf16)
    for (int it = 0; it < 8; ++it) {
        int f4 = it * 256 + t;              // 2048 float4 = 64 rows x 32
        int row = f4 >> 5, k4 = (f4 & 31) * 4;
        int g = m0 + row; if (g > NNODES - 1) g = NNODES - 1;
        f32x4 v = *((const f32x4*)(nf + g * 128) + (f4 & 31));
        *(bf16x4*)&a_lds[row * K1_PAD + k4] =
            (bf16x4){(bf16)v[0], (bf16)v[1], (bf16)v[2], (bf16)v[3]};
    }
    // stage At (already bf16)
    for (int it = 0; it < 8; ++it) {
        int c8 = it * 256 + t;              // 2048 chunks of 8 shorts
        int row = c8 >> 4, k8 = (c8 & 15) * 8;
        *(int4*)&b_lds[row * K1_PAD + k8] = *(const int4*)&At_g[row * 128 + k8];
    }
    __syncthreads();
    const int wave = t >> 6, lane = t & 63;
    const int n16 = lane & 15, quad = lane >> 4;
    const int mrow = wave * 16 + n16;
    f32x4 acc[8];
#pragma unroll
    for (int ct = 0; ct < 8; ++ct) acc[ct] = (f32x4){0.f, 0.f, 0.f, 0.f};
#pragma unroll
    for (int kt = 0; kt < 4; ++kt) {
        bf16x8 a = *(const bf16x8*)&a_lds[mrow * K1_PAD + kt * 32 + quad * 8];
#pragma unroll
        for (int ct = 0; ct < 8; ++ct) {
            bf16x8 b = *(const bf16x8*)&b_lds[(ct * 16 + n16) * K1_PAD + kt * 32 + quad * 8];
            acc[ct] = __builtin_amdgcn_mfma_f32_16x16x32_bf16(a, b, acc[ct], 0, 0, 0);
        }
    }
#pragma unroll
    for (int ct = 0; ct < 8; ++ct)
#pragma unroll
        for (int r = 0; r < 4; ++r) {
            int g = m0 + wave * 16 + quad * 4 + r;
            if (g < NNODES) y[g * 128 + ct * 16 + n16] = (bf16)acc[ct][r];
        }
}

// ---------------------------------------------------------------- kernel 2
// Per block: 64 edges. ef@Bm via MFMA, + a*(y_u+y_v) + c, row softmax, store.
// Gather: issued at kernel entry as bf16x8 (16B/lane; 1 instr = 4 full y rows),
// latency hidden under staging + MFMA. Redistributed via per-wave LDS scratch
// [16 edges][132 f32] (132-stride: read = 2-way banks = free, write = b128 floor).
#define K2_PAD 72    // 64 + 8 shorts: 144B rows (16B aligned), 2-way-bank-free
#define YW_S 132     // f32 row stride of yuv scratch

__global__ __launch_bounds__(256) void edge_kernel(
        const float* __restrict__ ef, const int* __restrict__ eidx,
        const bf16* __restrict__ Bmt_g, const float* __restrict__ cvec,
        const bf16* __restrict__ y, float* __restrict__ out) {
    __shared__ union {
        struct { bf16 ef[64 * K2_PAD]; bf16 b[128 * K2_PAD]; } s;  // 27648 B
        float yw[4 * 16 * YW_S];                                   // 33792 B
    } U;
    __shared__ float c_lds[128];
    const int t = threadIdx.x;
    const int e0 = blockIdx.x * 64;
    const int wave = t >> 6, lane = t & 63;
    const int quad = lane >> 4, n16 = lane & 15;   // quad = edge-within-4 / MFMA row group
                                                   // n16 = 16B-chunk / MFMA col lane
    // ---- early gather issue: 8 eidx + 8 bf16x8 y-loads, in flight during
    // staging + MFMA. One wave instruction covers 4 contiguous 256B y rows.
    float aa[4];
    bf16x8 yu8[4], yv8[4];
#pragma unroll
    for (int g = 0; g < 4; ++g) {
        int el = wave * 16 + g * 4 + quad;         // uniform across n16 lanes
        int uu = eidx[e0 + el];
        int vv = eidx[NEDGES + e0 + el];
        aa[g] = (uu == vv) ? 1.0f : 0.5f;
        yu8[g] = *(const bf16x8*)(y + (long)uu * 128 + n16 * 8);
        yv8[g] = *(const bf16x8*)(y + (long)vv * 128 + n16 * 8);
    }
    // ---- stage Bmt
    for (int it = 0; it < 4; ++it) {
        int c8 = it * 256 + t;              // 1024 chunks of 8 shorts
        int row = c8 >> 3, k8 = (c8 & 7) * 8;
        *(int4*)&U.s.b[row * K2_PAD + k8] = *(const int4*)&Bmt_g[row * 64 + k8];
    }
    if (t < 128) c_lds[t] = cvec[t];
    // ---- stage ef tile (fp32 -> bf16), non-temporal (keep y cached)
    for (int it = 0; it < 4; ++it) {
        int f4 = it * 256 + t;              // 1024 float4 = 64 rows x 16
        int row = f4 >> 4, k4 = (f4 & 15) * 4;
        f32x4 v = __builtin_nontemporal_load(
            ((const f32x4*)(ef + (e0 + row) * 64)) + (f4 & 15));
        *(bf16x4*)&U.s.ef[row * K2_PAD + k4] =
            (bf16x4){(bf16)v[0], (bf16)v[1], (bf16)v[2], (bf16)v[3]};
    }
    __syncthreads();
    // ---- MFMA: ef @ Bm
    const int mrow = wave * 16 + n16;
    f32x4 acc[8];
#pragma unroll
    for (int ct = 0; ct < 8; ++ct) acc[ct] = (f32x4){0.f, 0.f, 0.f, 0.f};
#pragma unroll
    for (int kt = 0; kt < 2; ++kt) {
        bf16x8 a = *(const bf16x8*)&U.s.ef[mrow * K2_PAD + kt * 32 + quad * 8];
#pragma unroll
        for (int ct = 0; ct < 8; ++ct) {
            bf16x8 b = *(const bf16x8*)&U.s.b[(ct * 16 + n16) * K2_PAD + kt * 32 + quad * 8];
            acc[ct] = __builtin_amdgcn_mfma_f32_16x16x32_bf16(a, b, acc[ct], 0, 0, 0);
        }
    }
    __syncthreads();   // all waves done reading U.s — safe to overwrite as U.yw
    // ---- a*(y_u+y_v) -> per-wave LDS scratch (write: 32B/lane contiguous)
    float* yw = U.yw + wave * (16 * YW_S);
#pragma unroll
    for (int g = 0; g < 4; ++g) {
        f32x4 lo, hi;
#pragma unroll
        for (int j = 0; j < 4; ++j) {
            lo[j] = aa[g] * ((float)yu8[g][j]     + (float)yv8[g][j]);
            hi[j] = aa[g] * ((float)yu8[g][j + 4] + (float)yv8[g][j + 4]);
        }
        float* dst = yw + (g * 4 + quad) * YW_S + n16 * 8;
        *(f32x4*)dst = lo;
        *(f32x4*)(dst + 4) = hi;
    }
    // ---- softmax over 128 cols (8 regs x 16 lanes per quad group) + store
#pragma unroll
    for (int r = 0; r < 4; ++r) {
        const float* yr = yw + (quad * 4 + r) * YW_S;
        float lgt[8];
        float m = -1e30f;
#pragma unroll
        for (int ct = 0; ct < 8; ++ct) {
            float l = acc[ct][r] + c_lds[ct * 16 + n16] + yr[ct * 16 + n16];
            lgt[ct] = l;
            m = fmaxf(m, l);
        }
        m = fmaxf(m, __shfl_xor(m, 1));
        m = fmaxf(m, __shfl_xor(m, 2));
        m = fmaxf(m, __shfl_xor(m, 4));
        m = fmaxf(m, __shfl_xor(m, 8));
        float p[8], s = 0.f;
#pragma unroll
        for (int ct = 0; ct < 8; ++ct) { p[ct] = __expf(lgt[ct] - m); s += p[ct]; }
        s += __shfl_xor(s, 1);
        s += __shfl_xor(s, 2);
        s += __shfl_xor(s, 4);
        s += __shfl_xor(s, 8);
        float inv = 1.0f / s;
        long eg = (long)e0 + wave * 16 + quad * 4 + r;
#pragma unroll
        for (int ct = 0; ct < 8; ++ct)
            __builtin_nontemporal_store(p[ct] * inv,
                                        &out[eg * 128 + ct * 16 + n16]);
    }
}

// ---------------------------------------------------------------- launch
extern "C" void kernel_launch(void* const* d_in, const int* in_sizes, int n_in,
                              void* d_out, int out_size, void* d_ws, size_t ws_size,
                              hipStream_t stream) {
    (void)in_sizes; (void)n_in; (void)out_size; (void)ws_size;
    const float* nf  = (const float*)d_in[0];
    const float* ef  = (const float*)d_in[1];
    const int*  eidx = (const int*)d_in[2];
    const float* W1  = (const float*)d_in[3];
    const float* b1  = (const float*)d_in[4];
    // d_in[5] (W2), d_in[6] (b2), d_in[9] (Wa), d_in[10] (ba): dead in reference
    const float* W3  = (const float*)d_in[7];
    const float* b3  = (const float*)d_in[8];
    float* out = (float*)d_out;

    char* ws = (char*)d_ws;
    bf16*  y    = (bf16*)ws;                               // 50000*128*2 = 12.8 MB
    bf16*  At   = (bf16*)(ws + 26u * 1024 * 1024);         // 32 KB
    bf16*  Bmt  = (bf16*)(ws + 26u * 1024 * 1024 + 64 * 1024);   // 16 KB
    float* cvec = (float*)(ws + 26u * 1024 * 1024 + 96 * 1024);  // 512 B

    prep_kernel<<<129, 128, 0, stream>>>(W1, b1, W3, b3, At, Bmt, cvec);
    node_proj_kernel<<<(NNODES + 63) / 64, 256, 0, stream>>>(nf, At, y);
    edge_kernel<<<NEDGES / 64, 256, 0, stream>>>(ef, eidx, Bmt, cvec, y, out);
}

// Round 4
// 516.353 us; speedup vs baseline: 1.0495x; 1.0495x over previous
//
#include <hip/hip_runtime.h>
#include <hip/hip_bf16.h>

// EdgeAttentionEmbedding collapsed form:
//   softmax([s,s]) == [0.5,0.5]  =>  attention branch (W2,b2,Wa,ba) is dead.
//   out[e] = row_softmax( a_e*(nf[u]+nf[v]) @ A + ef[e] @ Bm + c )
//   A  = 0.5*sum_h W1_h @ W3_h[:128]   (128x128)
//   Bm = 0.5*sum_h W3_h[128:192]       (64x128)
//   c  = sum_h b1_h @ W3_h[:128] + 0.5*sum_h b3_h
//   a_e = (u==v) ? 1.0 : 0.5
// y = nf @ A precomputed over N=50k nodes (12.8x fewer FLOPs than per-edge).
// y stored in BF16: halves the random-gather volume in edge_kernel and keeps
// the gather table at 12.8 MB (L2/L3-resident). Streaming reads (nf, ef) and
// the out store are non-temporal so they don't evict y.
// NOTE (round-3 lesson): do NOT issue the y gathers before staging — they
// depend on eidx (program-order VMEM issue => stalls the staging stream).
// The post-MFMA gather position is already latency-hidden by occupancy.

#define NNODES 50000
#define NEDGES 640000

typedef __bf16 bf16;
typedef __bf16 bf16x4 __attribute__((ext_vector_type(4)));
typedef __bf16 bf16x8 __attribute__((ext_vector_type(8)));
typedef float f32x4 __attribute__((ext_vector_type(4)));

// ---------------------------------------------------------------- kernel 0
// Fold weights: At[c][k] = A[k][c] (bf16), Bmt[c][k] = Bm[k][c] (bf16), cvec f32.
__global__ void prep_kernel(const float* __restrict__ W1, const float* __restrict__ b1,
                            const float* __restrict__ W3, const float* __restrict__ b3,
                            bf16* __restrict__ At, bf16* __restrict__ Bmt,
                            float* __restrict__ cvec) {
    int j = threadIdx.x;   // output column 0..127
    int i = blockIdx.x;    // 0..127: A row i; 128: c + Bmt
    if (i < 128) {
        float acc = 0.f;
        for (int h = 0; h < 2; ++h) {
            const float* w1 = W1 + h * 128 * 128 + i * 128;
            const float* w3 = W3 + h * 192 * 128;
            for (int k = 0; k < 128; ++k)
                acc += w1[k] * w3[k * 128 + j];
        }
        At[j * 128 + i] = (bf16)(0.5f * acc);
    } else {
        float acc = 0.f;
        for (int h = 0; h < 2; ++h) {
            const float* w3 = W3 + h * 192 * 128;
            for (int k = 0; k < 128; ++k)
                acc += b1[h * 128 + k] * w3[k * 128 + j];
        }
        acc += 0.5f * (b3[j] + b3[128 + j]);
        cvec[j] = acc;
        for (int k = 0; k < 64; ++k) {
            float bm = 0.5f * (W3[(128 + k) * 128 + j] +
                               W3[192 * 128 + (128 + k) * 128 + j]);
            Bmt[j * 64 + k] = (bf16)bm;
        }
    }
}

// ---------------------------------------------------------------- kernel 1
// y[n][c] = (nf @ A)[n][c], bf16 out. Tile: 64 rows x 128 cols per block (4 waves).
#define K1_PAD 136   // 128 + 8 shorts: 272B rows (16B aligned), 2-way-bank-free

__global__ __launch_bounds__(256) void node_proj_kernel(
        const float* __restrict__ nf, const bf16* __restrict__ At_g,
        bf16* __restrict__ y) {
    __shared__ bf16 a_lds[64 * K1_PAD];
    __shared__ bf16 b_lds[128 * K1_PAD];
    const int t = threadIdx.x;
    const int m0 = blockIdx.x * 64;
    // stage nf tile (fp32 -> bf16), non-temporal (streamed once)
    for (int it = 0; it < 8; ++it) {
        int f4 = it * 256 + t;              // 2048 float4 = 64 rows x 32
        int row = f4 >> 5, k4 = (f4 & 31) * 4;
        int g = m0 + row; if (g > NNODES - 1) g = NNODES - 1;
        f32x4 v = __builtin_nontemporal_load(
            (const f32x4*)(nf + g * 128) + (f4 & 31));
        *(bf16x4*)&a_lds[row * K1_PAD + k4] =
            (bf16x4){(bf16)v[0], (bf16)v[1], (bf16)v[2], (bf16)v[3]};
    }
    // stage At (already bf16)
    for (int it = 0; it < 8; ++it) {
        int c8 = it * 256 + t;              // 2048 chunks of 8 shorts
        int row = c8 >> 4, k8 = (c8 & 15) * 8;
        *(int4*)&b_lds[row * K1_PAD + k8] = *(const int4*)&At_g[row * 128 + k8];
    }
    __syncthreads();
    const int wave = t >> 6, lane = t & 63;
    const int n16 = lane & 15, quad = lane >> 4;
    const int mrow = wave * 16 + n16;
    f32x4 acc[8];
#pragma unroll
    for (int ct = 0; ct < 8; ++ct) acc[ct] = (f32x4){0.f, 0.f, 0.f, 0.f};
#pragma unroll
    for (int kt = 0; kt < 4; ++kt) {
        bf16x8 a = *(const bf16x8*)&a_lds[mrow * K1_PAD + kt * 32 + quad * 8];
#pragma unroll
        for (int ct = 0; ct < 8; ++ct) {
            bf16x8 b = *(const bf16x8*)&b_lds[(ct * 16 + n16) * K1_PAD + kt * 32 + quad * 8];
            acc[ct] = __builtin_amdgcn_mfma_f32_16x16x32_bf16(a, b, acc[ct], 0, 0, 0);
        }
    }
#pragma unroll
    for (int ct = 0; ct < 8; ++ct)
#pragma unroll
        for (int r = 0; r < 4; ++r) {
            int g = m0 + wave * 16 + quad * 4 + r;
            if (g < NNODES) y[g * 128 + ct * 16 + n16] = (bf16)acc[ct][r];
        }
}

// ---------------------------------------------------------------- kernel 2
// Per block: 64 edges. ef@Bm via MFMA, + a*(y_u+y_v) + c, row softmax, store.
#define K2_PAD 72    // 64 + 8 shorts: 144B rows (16B aligned), 2-way-bank-free

__global__ __launch_bounds__(256) void edge_kernel(
        const float* __restrict__ ef, const int* __restrict__ eidx,
        const bf16* __restrict__ Bmt_g, const float* __restrict__ cvec,
        const bf16* __restrict__ y, float* __restrict__ out) {
    __shared__ bf16 ef_lds[64 * K2_PAD];
    __shared__ bf16 b_lds[128 * K2_PAD];
    __shared__ int u_lds[64], v_lds[64];
    __shared__ float a_lds[64], c_lds[128];
    const int t = threadIdx.x;
    const int e0 = blockIdx.x * 64;
    // stage Bmt
    for (int it = 0; it < 4; ++it) {
        int c8 = it * 256 + t;              // 1024 chunks of 8 shorts
        int row = c8 >> 3, k8 = (c8 & 7) * 8;
        *(int4*)&b_lds[row * K2_PAD + k8] = *(const int4*)&Bmt_g[row * 64 + k8];
    }
    if (t < 128) c_lds[t] = cvec[t];
    if (t < 64) {
        int u = eidx[e0 + t], v = eidx[NEDGES + e0 + t];
        u_lds[t] = u; v_lds[t] = v;
        a_lds[t] = (u == v) ? 1.0f : 0.5f;
    }
    // stage ef tile (fp32 -> bf16), non-temporal (streamed once, keep y cached)
    for (int it = 0; it < 4; ++it) {
        int f4 = it * 256 + t;              // 1024 float4 = 64 rows x 16
        int row = f4 >> 4, k4 = (f4 & 15) * 4;
        f32x4 v = __builtin_nontemporal_load(
            ((const f32x4*)(ef + (e0 + row) * 64)) + (f4 & 15));
        *(bf16x4*)&ef_lds[row * K2_PAD + k4] =
            (bf16x4){(bf16)v[0], (bf16)v[1], (bf16)v[2], (bf16)v[3]};
    }
    __syncthreads();
    const int wave = t >> 6, lane = t & 63;
    const int n16 = lane & 15, quad = lane >> 4;
    const int mrow = wave * 16 + n16;
    f32x4 acc[8];
#pragma unroll
    for (int ct = 0; ct < 8; ++ct) acc[ct] = (f32x4){0.f, 0.f, 0.f, 0.f};
#pragma unroll
    for (int kt = 0; kt < 2; ++kt) {
        bf16x8 a = *(const bf16x8*)&ef_lds[mrow * K2_PAD + kt * 32 + quad * 8];
#pragma unroll
        for (int ct = 0; ct < 8; ++ct) {
            bf16x8 b = *(const bf16x8*)&b_lds[(ct * 16 + n16) * K2_PAD + kt * 32 + quad * 8];
            acc[ct] = __builtin_amdgcn_mfma_f32_16x16x32_bf16(a, b, acc[ct], 0, 0, 0);
        }
    }
    // gather a*(y_u + y_v) in bf16 (256B rows); D layout: row = quad*4+r, col = ct*16+n16
    float yuv[8][4];
#pragma unroll
    for (int r = 0; r < 4; ++r) {
        int el = wave * 16 + quad * 4 + r;
        const bf16* __restrict__ yu = y + (long)u_lds[el] * 128;
        const bf16* __restrict__ yv = y + (long)v_lds[el] * 128;
        float aa = a_lds[el];
#pragma unroll
        for (int ct = 0; ct < 8; ++ct)
            yuv[ct][r] = aa * ((float)yu[ct * 16 + n16] + (float)yv[ct * 16 + n16]);
    }
    // softmax over 128 cols (8 regs x 16 lanes within each quad group) + store
#pragma unroll
    for (int r = 0; r < 4; ++r) {
        float lgt[8];
        float m = -1e30f;
#pragma unroll
        for (int ct = 0; ct < 8; ++ct) {
            float l = acc[ct][r] + c_lds[ct * 16 + n16] + yuv[ct][r];
            lgt[ct] = l;
            m = fmaxf(m, l);
        }
        m = fmaxf(m, __shfl_xor(m, 1));
        m = fmaxf(m, __shfl_xor(m, 2));
        m = fmaxf(m, __shfl_xor(m, 4));
        m = fmaxf(m, __shfl_xor(m, 8));
        float p[8], s = 0.f;
#pragma unroll
        for (int ct = 0; ct < 8; ++ct) { p[ct] = __expf(lgt[ct] - m); s += p[ct]; }
        s += __shfl_xor(s, 1);
        s += __shfl_xor(s, 2);
        s += __shfl_xor(s, 4);
        s += __shfl_xor(s, 8);
        float inv = 1.0f / s;
        long eg = (long)e0 + wave * 16 + quad * 4 + r;
#pragma unroll
        for (int ct = 0; ct < 8; ++ct)
            __builtin_nontemporal_store(p[ct] * inv,
                                        &out[eg * 128 + ct * 16 + n16]);
    }
}

// ---------------------------------------------------------------- launch
extern "C" void kernel_launch(void* const* d_in, const int* in_sizes, int n_in,
                              void* d_out, int out_size, void* d_ws, size_t ws_size,
                              hipStream_t stream) {
    (void)in_sizes; (void)n_in; (void)out_size; (void)ws_size;
    const float* nf  = (const float*)d_in[0];
    const float* ef  = (const float*)d_in[1];
    const int*  eidx = (const int*)d_in[2];
    const float* W1  = (const float*)d_in[3];
    const float* b1  = (const float*)d_in[4];
    // d_in[5] (W2), d_in[6] (b2), d_in[9] (Wa), d_in[10] (ba): dead in reference
    const float* W3  = (const float*)d_in[7];
    const float* b3  = (const float*)d_in[8];
    float* out = (float*)d_out;

    char* ws = (char*)d_ws;
    bf16*  y    = (bf16*)ws;                               // 50000*128*2 = 12.8 MB
    bf16*  At   = (bf16*)(ws + 26u * 1024 * 1024);         // 32 KB
    bf16*  Bmt  = (bf16*)(ws + 26u * 1024 * 1024 + 64 * 1024);   // 16 KB
    float* cvec = (float*)(ws + 26u * 1024 * 1024 + 96 * 1024);  // 512 B

    prep_kernel<<<129, 128, 0, stream>>>(W1, b1, W3, b3, At, Bmt, cvec);
    node_proj_kernel<<<(NNODES + 63) / 64, 256, 0, stream>>>(nf, At, y);
    edge_kernel<<<NEDGES / 64, 256, 0, stream>>>(ef, eidx, Bmt, cvec, y, out);
}